// Round 1
// baseline (141.333 us; speedup 1.0000x reference)
//
#include <hip/hip_runtime.h>
#include <hip/hip_bf16.h>

#define S_ 1024
#define D_ 128
#define V_ 100000
#define N_ 4096
#define VPAD_ 100096   // 782 * 128
#define NTILES_ 782
#define NSPLIT_ 16

typedef __attribute__((ext_vector_type(4))) float f32x4;
typedef __attribute__((ext_vector_type(8))) short bf16x8;

__device__ __forceinline__ void gload16(const void* g, void* l) {
    __builtin_amdgcn_global_load_lds(
        (const __attribute__((address_space(1))) void*)g,
        (__attribute__((address_space(3))) void*)l, 16, 0, 0);
}

// ---- kernel 1: normalize K rows -> bf16, zero-fill pad rows [V_, VPAD_) ----
__global__ void knorm_kernel(const float* __restrict__ K, __hip_bfloat16* __restrict__ Kn) {
    int w = (blockIdx.x * blockDim.x + threadIdx.x) >> 6;
    int lane = threadIdx.x & 63;
    if (w >= VPAD_) return;
    unsigned int* dst = (unsigned int*)(Kn + (size_t)w * D_);
    if (w >= V_) { dst[lane] = 0u; return; }
    float2 v = ((const float2*)(K + (size_t)w * D_))[lane];
    float ss = v.x * v.x + v.y * v.y;
    #pragma unroll
    for (int off = 32; off; off >>= 1) ss += __shfl_xor(ss, off);
    float rn = rsqrtf(ss);
    __hip_bfloat162 o;
    o.x = __float2bfloat16(v.x * rn);
    o.y = __float2bfloat16(v.y * rn);
    ((__hip_bfloat162*)dst)[lane] = o;
}

// ---- kernel 2: gather + normalize Q rows -> bf16 ----
__global__ void qnorm_kernel(const float* __restrict__ Q, const int* __restrict__ loc,
                             __hip_bfloat16* __restrict__ Qn) {
    int w = (blockIdx.x * blockDim.x + threadIdx.x) >> 6;
    int lane = threadIdx.x & 63;
    if (w >= N_) return;
    int b = loc[2 * w], s = loc[2 * w + 1];
    float2 v = ((const float2*)(Q + ((size_t)b * S_ + (size_t)s) * D_))[lane];
    float ss = v.x * v.x + v.y * v.y;
    #pragma unroll
    for (int off = 32; off; off >>= 1) ss += __shfl_xor(ss, off);
    float rn = rsqrtf(ss);
    __hip_bfloat162 o;
    o.x = __float2bfloat16(v.x * rn);
    o.y = __float2bfloat16(v.y * rn);
    ((__hip_bfloat162*)(Qn + (size_t)w * D_))[lane] = o;
}

__global__ void zeroS_kernel(float* __restrict__ S) {
    S[blockIdx.x * 256 + threadIdx.x] = 0.f;
}

// ---- kernel 3: main  sum_v exp(q_n . k_v)  via bf16 MFMA ----
// grid (32, NSPLIT_), block 256 (4 waves, 2x2 of 64x64). Tile 128n x 128v, K=128.
__global__ __launch_bounds__(256, 2) void ce_main(
    const __hip_bfloat16* __restrict__ Qn,
    const __hip_bfloat16* __restrict__ Kn,
    float* __restrict__ Ssum)
{
    __shared__ char lds[65536];
    char* qlds = lds;
    char* klds = lds + 32768;

    const int tid  = threadIdx.x;
    const int lane = tid & 63;
    const int wave = tid >> 6;
    const int wr = wave >> 1;
    const int wc = wave & 1;
    const int nb = blockIdx.x;
    const int split = blockIdx.y;

    // stage Q tile (contiguous 32KB) with pre-swizzled global source:
    // LDS linear dest; stored[L] = global[L ^ (((L>>8)&7)<<4)]  (involution, row bits >= 8)
    {
        const char* src = (const char*)Qn + (size_t)nb * 32768;
        #pragma unroll
        for (int it = 0; it < 8; ++it) {
            int L = (it * 256 + tid) << 4;
            int G = L ^ (((L >> 8) & 7) << 4);
            gload16(src + G, qlds + L);
        }
    }

    float psum[4][4];
    #pragma unroll
    for (int m = 0; m < 4; ++m)
        #pragma unroll
        for (int q = 0; q < 4; ++q) psum[m][q] = 0.f;

    const int r0 = lane & 15;
    const int kb = (lane >> 4) << 4;    // byte offset of this lane's 8 k-elems
    const int axor = (r0 & 7) << 4;     // read-side XOR swizzle (row&7)<<4

    for (int t = split; t < NTILES_; t += NSPLIT_) {
        const char* ksrc = (const char*)Kn + (size_t)t * 32768;
        #pragma unroll
        for (int it = 0; it < 8; ++it) {
            int L = (it * 256 + tid) << 4;
            int G = L ^ (((L >> 8) & 7) << 4);
            gload16(ksrc + G, klds + L);
        }
        __syncthreads();   // compiler emits vmcnt(0) drain before barrier

        bf16x8 bfr[4][4];
        #pragma unroll
        for (int nn = 0; nn < 4; ++nn) {
            int col = wc * 64 + nn * 16 + r0;
            #pragma unroll
            for (int kk = 0; kk < 4; ++kk) {
                int addr = (col * 256 + kk * 64 + kb) ^ axor;
                bfr[nn][kk] = *(const bf16x8*)(klds + addr);
            }
        }
        #pragma unroll
        for (int m = 0; m < 4; ++m) {
            int row = wr * 64 + m * 16 + r0;
            bf16x8 afr[4];
            #pragma unroll
            for (int kk = 0; kk < 4; ++kk) {
                int addr = (row * 256 + kk * 64 + kb) ^ axor;
                afr[kk] = *(const bf16x8*)(qlds + addr);
            }
            #pragma unroll
            for (int nn = 0; nn < 4; ++nn) {
                f32x4 acc = {0.f, 0.f, 0.f, 0.f};
                #pragma unroll
                for (int kk = 0; kk < 4; ++kk)
                    acc = __builtin_amdgcn_mfma_f32_16x16x32_bf16(afr[kk], bfr[nn][kk], acc, 0, 0, 0);
                #pragma unroll
                for (int q = 0; q < 4; ++q)
                    psum[m][q] += __expf(acc[q]);   // logits in [-1,1]: no max needed
            }
        }
        __syncthreads();
    }

    // reduce over the 16 lanes holding the same rows (different cols), then atomics
    #pragma unroll
    for (int m = 0; m < 4; ++m) {
        #pragma unroll
        for (int q = 0; q < 4; ++q) {
            float v = psum[m][q];
            v += __shfl_xor(v, 1);
            v += __shfl_xor(v, 2);
            v += __shfl_xor(v, 4);
            v += __shfl_xor(v, 8);
            if (r0 == 0) {
                int row = nb * 128 + wr * 64 + m * 16 + ((lane >> 4) << 2) + q;
                atomicAdd(&Ssum[row], v);
            }
        }
    }
}

// ---- kernel 4: per-row term = log(S - 96) - q.k_label ----
__global__ void term_kernel(const __hip_bfloat16* __restrict__ Qn,
                            const __hip_bfloat16* __restrict__ Kn,
                            const int* __restrict__ labels,
                            const float* __restrict__ Ssum,
                            float* __restrict__ T) {
    int w = (blockIdx.x * blockDim.x + threadIdx.x) >> 6;
    int lane = threadIdx.x & 63;
    if (w >= N_) return;
    int lab = labels[w];
    __hip_bfloat162 q2 = ((const __hip_bfloat162*)(Qn + (size_t)w * D_))[lane];
    __hip_bfloat162 k2 = ((const __hip_bfloat162*)(Kn + (size_t)lab * D_))[lane];
    float d = __bfloat162float(q2.x) * __bfloat162float(k2.x)
            + __bfloat162float(q2.y) * __bfloat162float(k2.y);
    #pragma unroll
    for (int off = 32; off; off >>= 1) d += __shfl_xor(d, off);
    if (lane == 0) T[w] = logf(Ssum[w] - 96.0f) - d;
}

// ---- kernel 5: mean over N ----
__global__ void reduce_kernel(const float* __restrict__ T, float* __restrict__ out) {
    __shared__ float sm[4];
    float s = 0.f;
    for (int i = threadIdx.x; i < N_; i += 256) s += T[i];
    #pragma unroll
    for (int off = 32; off; off >>= 1) s += __shfl_xor(s, off);
    if ((threadIdx.x & 63) == 0) sm[threadIdx.x >> 6] = s;
    __syncthreads();
    if (threadIdx.x == 0) out[0] = (sm[0] + sm[1] + sm[2] + sm[3]) * (1.0f / (float)N_);
}

extern "C" void kernel_launch(void* const* d_in, const int* in_sizes, int n_in,
                              void* d_out, int out_size, void* d_ws, size_t ws_size,
                              hipStream_t stream) {
    (void)in_sizes; (void)n_in; (void)out_size; (void)ws_size;
    const float* Q   = (const float*)d_in[0];
    const float* K   = (const float*)d_in[1];
    const int* loc   = (const int*)d_in[2];
    const int* labels= (const int*)d_in[3];
    float* out = (float*)d_out;

    char* ws = (char*)d_ws;
    __hip_bfloat16* Kn = (__hip_bfloat16*)ws;                       // VPAD_*128*2 = 25,624,576 B
    __hip_bfloat16* Qn = (__hip_bfloat16*)(ws + 25624576);          // N_*128*2   =  1,048,576 B
    float* Ssum        = (float*)(ws + 25624576 + 1048576);         // N_*4
    float* T           = Ssum + N_;                                  // N_*4

    knorm_kernel<<<VPAD_ / 4, 256, 0, stream>>>(K, Kn);
    qnorm_kernel<<<N_ / 4, 256, 0, stream>>>(Q, loc, Qn);
    zeroS_kernel<<<N_ / 256, 256, 0, stream>>>(Ssum);
    ce_main<<<dim3(N_ / 128, NSPLIT_), 256, 0, stream>>>(Qn, Kn, Ssum);
    term_kernel<<<N_ / 4, 256, 0, stream>>>(Qn, Kn, labels, Ssum, T);
    reduce_kernel<<<1, 256, 0, stream>>>(T, out);
}

// Round 2
// 137.521 us; speedup vs baseline: 1.0277x; 1.0277x over previous
//
#include <hip/hip_runtime.h>
#include <hip/hip_bf16.h>

#define S_ 1024
#define D_ 128
#define V_ 100000
#define N_ 4096
#define VPAD_ 100096   // 782 * 128
#define NTILES_ 782
#define NSPLIT_ 16

typedef __attribute__((ext_vector_type(4))) float f32x4;
typedef __attribute__((ext_vector_type(8))) short bf16x8;

#define LOG2E_ 1.4426950408889634f
#define LN2_   0.6931471805599453f

__device__ __forceinline__ void gload16(const void* g, void* l) {
    __builtin_amdgcn_global_load_lds(
        (const __attribute__((address_space(1))) void*)g,
        (__attribute__((address_space(3))) void*)l, 16, 0, 0);
}

__device__ __forceinline__ float exp2_fast(float x) {
#if __has_builtin(__builtin_amdgcn_exp2f)
    return __builtin_amdgcn_exp2f(x);
#else
    return exp2f(x);
#endif
}

// ---- kernel 1: normalize K rows -> bf16, zero-fill pad rows [V_, VPAD_) ----
__global__ void knorm_kernel(const float* __restrict__ K, __hip_bfloat16* __restrict__ Kn) {
    int w = (blockIdx.x * blockDim.x + threadIdx.x) >> 6;
    int lane = threadIdx.x & 63;
    if (w >= VPAD_) return;
    unsigned int* dst = (unsigned int*)(Kn + (size_t)w * D_);
    if (w >= V_) { dst[lane] = 0u; return; }
    float2 v = ((const float2*)(K + (size_t)w * D_))[lane];
    float ss = v.x * v.x + v.y * v.y;
    #pragma unroll
    for (int off = 32; off; off >>= 1) ss += __shfl_xor(ss, off);
    float rn = rsqrtf(ss);
    __hip_bfloat162 o;
    o.x = __float2bfloat16(v.x * rn);
    o.y = __float2bfloat16(v.y * rn);
    ((__hip_bfloat162*)dst)[lane] = o;
}

// ---- kernel 2: gather + normalize Q rows -> bf16, PRE-SCALED by log2(e) ----
__global__ void qnorm_kernel(const float* __restrict__ Q, const int* __restrict__ loc,
                             __hip_bfloat16* __restrict__ Qn) {
    int w = (blockIdx.x * blockDim.x + threadIdx.x) >> 6;
    int lane = threadIdx.x & 63;
    if (w >= N_) return;
    int b = loc[2 * w], s = loc[2 * w + 1];
    float2 v = ((const float2*)(Q + ((size_t)b * S_ + (size_t)s) * D_))[lane];
    float ss = v.x * v.x + v.y * v.y;
    #pragma unroll
    for (int off = 32; off; off >>= 1) ss += __shfl_xor(ss, off);
    float rn = rsqrtf(ss) * LOG2E_;   // fold log2(e): logits land in exp2 domain
    __hip_bfloat162 o;
    o.x = __float2bfloat16(v.x * rn);
    o.y = __float2bfloat16(v.y * rn);
    ((__hip_bfloat162*)(Qn + (size_t)w * D_))[lane] = o;
}

__global__ void zeroS_kernel(float* __restrict__ S) {
    S[blockIdx.x * 256 + threadIdx.x] = 0.f;
}

// ---- kernel 3: main  sum_v exp(q . k_v)  via bf16 MFMA ----
// grid (32, NSPLIT_), block 256 (4 waves, 2x2 of 64x64 output each).
// Q fragments live in registers (loop-invariant). K tiles are staged into LDS
// in FRAGMENT ORDER: chunk(wc,nn,kk) = wc*16+nn*4+kk, LDS[chunk*1024 + lane*16]
// holds exactly what ds_read_b128 wants -> linear reads, zero bank conflicts.
__global__ __launch_bounds__(256, 2) void ce_main(
    const __hip_bfloat16* __restrict__ Qn,
    const __hip_bfloat16* __restrict__ Kn,
    float* __restrict__ Ssum)
{
    __shared__ char klds[65536];   // 2 x 32KB double buffer

    const int tid  = threadIdx.x;
    const int lane = tid & 63;
    const int wv   = tid >> 6;     // wave id 0..3 (also = kk for staging)
    const int wr = wv >> 1;
    const int wc = wv & 1;
    const int nb = blockIdx.x;
    const int split = blockIdx.y;

    // staging offsets: chunk = it*4 + wv; wc_s=it>>2, nn_s=it&3, kk_s=wv
    // G(chunk,lane) = (wc_s*64 + nn_s*16 + (lane&15))*256 + kk_s*64 + (lane>>4)*16
    const int goff = ((lane & 15) << 8) + (wv << 6) + ((lane >> 4) << 4);
    const int loff = (wv << 10) + (lane << 4);

    // ---- Q fragments -> registers (loop-invariant), direct from global ----
    bf16x8 afr[4][4];
    {
        const char* qsrc = (const char*)Qn + (size_t)nb * 32768
                         + (wr * 64 + (lane & 15)) * 256 + ((lane >> 4) << 4);
        #pragma unroll
        for (int m = 0; m < 4; ++m)
            #pragma unroll
            for (int kk = 0; kk < 4; ++kk)
                afr[m][kk] = *(const bf16x8*)(qsrc + m * 4096 + kk * 64);
    }

    // ---- prologue: stage first K tile into buffer 0 ----
    {
        const char* src = (const char*)Kn + (size_t)split * 32768 + goff;
        #pragma unroll
        for (int it = 0; it < 8; ++it)
            gload16(src + (it & 3) * 4096 + (it >> 2) * 16384,
                    klds + loff + it * 4096);
    }

    float psum[4][4];
    #pragma unroll
    for (int m = 0; m < 4; ++m)
        #pragma unroll
        for (int q = 0; q < 4; ++q) psum[m][q] = 0.f;

    __syncthreads();   // implicit vmcnt(0): buffer 0 ready

    int cur = 0;
    for (int t = split; t < NTILES_; t += NSPLIT_) {
        // stage next tile into the other buffer (loads fly during compute)
        int tn = t + NSPLIT_;
        if (tn < NTILES_) {
            const char* src = (const char*)Kn + (size_t)tn * 32768 + goff;
            char* dst = klds + ((cur ^ 1) << 15) + loff;
            #pragma unroll
            for (int it = 0; it < 8; ++it)
                gload16(src + (it & 3) * 4096 + (it >> 2) * 16384,
                        dst + it * 4096);
        }

        // fragment-ordered reads: base + compile-time offsets, conflict-free
        const char* base = klds + (cur << 15) + (wc << 14) + (lane << 4);
        bf16x8 bfr[4][4];
        #pragma unroll
        for (int nn = 0; nn < 4; ++nn)
            #pragma unroll
            for (int kk = 0; kk < 4; ++kk)
                bfr[nn][kk] = *(const bf16x8*)(base + nn * 4096 + kk * 1024);

        #pragma unroll
        for (int m = 0; m < 4; ++m) {
            #pragma unroll
            for (int nn = 0; nn < 4; ++nn) {
                f32x4 acc = {0.f, 0.f, 0.f, 0.f};
                #pragma unroll
                for (int kk = 0; kk < 4; ++kk)
                    acc = __builtin_amdgcn_mfma_f32_16x16x32_bf16(afr[m][kk], bfr[nn][kk], acc, 0, 0, 0);
                #pragma unroll
                for (int q = 0; q < 4; ++q)
                    psum[m][q] += exp2_fast(acc[q]);   // logits bounded: no max needed
            }
        }

        __syncthreads();   // drains vmcnt: next buffer ready, this one reusable
        cur ^= 1;
    }

    // reduce over the 16 lanes holding the same rows (different cols), then atomics
    #pragma unroll
    for (int m = 0; m < 4; ++m) {
        #pragma unroll
        for (int q = 0; q < 4; ++q) {
            float v = psum[m][q];
            v += __shfl_xor(v, 1);
            v += __shfl_xor(v, 2);
            v += __shfl_xor(v, 4);
            v += __shfl_xor(v, 8);
            if ((lane & 15) == 0) {
                int row = nb * 128 + wr * 64 + m * 16 + ((lane >> 4) << 2) + q;
                atomicAdd(&Ssum[row], v);
            }
        }
    }
}

// ---- kernel 4: per-row term = log(S - 96) - true_logit ----
// Qn is scaled by log2(e): true_logit = (qn . k) * ln2
__global__ void term_kernel(const __hip_bfloat16* __restrict__ Qn,
                            const __hip_bfloat16* __restrict__ Kn,
                            const int* __restrict__ labels,
                            const float* __restrict__ Ssum,
                            float* __restrict__ T) {
    int w = (blockIdx.x * blockDim.x + threadIdx.x) >> 6;
    int lane = threadIdx.x & 63;
    if (w >= N_) return;
    int lab = labels[w];
    __hip_bfloat162 q2 = ((const __hip_bfloat162*)(Qn + (size_t)w * D_))[lane];
    __hip_bfloat162 k2 = ((const __hip_bfloat162*)(Kn + (size_t)lab * D_))[lane];
    float d = __bfloat162float(q2.x) * __bfloat162float(k2.x)
            + __bfloat162float(q2.y) * __bfloat162float(k2.y);
    #pragma unroll
    for (int off = 32; off; off >>= 1) d += __shfl_xor(d, off);
    if (lane == 0) T[w] = logf(Ssum[w] - 96.0f) - d * LN2_;
}

// ---- kernel 5: mean over N ----
__global__ void reduce_kernel(const float* __restrict__ T, float* __restrict__ out) {
    __shared__ float sm[4];
    float s = 0.f;
    for (int i = threadIdx.x; i < N_; i += 256) s += T[i];
    #pragma unroll
    for (int off = 32; off; off >>= 1) s += __shfl_xor(s, off);
    if ((threadIdx.x & 63) == 0) sm[threadIdx.x >> 6] = s;
    __syncthreads();
    if (threadIdx.x == 0) out[0] = (sm[0] + sm[1] + sm[2] + sm[3]) * (1.0f / (float)N_);
}

extern "C" void kernel_launch(void* const* d_in, const int* in_sizes, int n_in,
                              void* d_out, int out_size, void* d_ws, size_t ws_size,
                              hipStream_t stream) {
    (void)in_sizes; (void)n_in; (void)out_size; (void)ws_size;
    const float* Q   = (const float*)d_in[0];
    const float* K   = (const float*)d_in[1];
    const int* loc   = (const int*)d_in[2];
    const int* labels= (const int*)d_in[3];
    float* out = (float*)d_out;

    char* ws = (char*)d_ws;
    __hip_bfloat16* Kn = (__hip_bfloat16*)ws;                       // VPAD_*128*2 = 25,624,576 B
    __hip_bfloat16* Qn = (__hip_bfloat16*)(ws + 25624576);          // N_*128*2   =  1,048,576 B
    float* Ssum        = (float*)(ws + 25624576 + 1048576);         // N_*4
    float* T           = Ssum + N_;                                  // N_*4

    knorm_kernel<<<VPAD_ / 4, 256, 0, stream>>>(K, Kn);
    qnorm_kernel<<<N_ / 4, 256, 0, stream>>>(Q, loc, Qn);
    zeroS_kernel<<<N_ / 256, 256, 0, stream>>>(Ssum);
    ce_main<<<dim3(N_ / 128, NSPLIT_), 256, 0, stream>>>(Qn, Kn, Ssum);
    term_kernel<<<N_ / 4, 256, 0, stream>>>(Qn, Kn, labels, Ssum, T);
    reduce_kernel<<<1, 256, 0, stream>>>(T, out);
}